// Round 1
// baseline (538.086 us; speedup 1.0000x reference)
//
#include <hip/hip_runtime.h>

#define DIM 1536
#define NH  12
#define HD  128
#define SEQ 4096

typedef unsigned short u16;
typedef unsigned int   u32;
typedef __attribute__((ext_vector_type(8))) short bf16x8;
typedef __attribute__((ext_vector_type(4))) float f32x4;

static __device__ __forceinline__ u16 f2bf(float f) {
    u32 u = __float_as_uint(f);
    u32 r = u + 0x7FFFu + ((u >> 16) & 1u);
    return (u16)(r >> 16);
}
static __device__ __forceinline__ float bf2f(u16 h) {
    return __uint_as_float(((u32)h) << 16);
}
static __device__ __forceinline__ u32 pack2(float a, float b) {
    return (u32)f2bf(a) | ((u32)f2bf(b) << 16);
}

#define GLL(g, s) __builtin_amdgcn_global_load_lds( \
    (const __attribute__((address_space(1))) void*)(g), \
    (__attribute__((address_space(3))) void*)(s), 16, 0, 0)

// ---------------- x -> bf16 (8 elems/thread) ----------------
__global__ __launch_bounds__(256) void k_cvt_x(const float* __restrict__ x, u16* __restrict__ xb) {
    int gid = blockIdx.x * 256 + threadIdx.x;      // 786432 threads
    const float4* p = (const float4*)x + (size_t)gid * 2;
    float4 a = p[0], b = p[1];
    uint4 o;
    o.x = pack2(a.x, a.y); o.y = pack2(a.z, a.w);
    o.z = pack2(b.x, b.y); o.w = pack2(b.z, b.w);
    *(uint4*)(xb + (size_t)gid * 8) = o;
}

// ---------------- weight transpose + bf16 ----------------
// out[n][d] = W[d][n]; z=0..2 -> wqkv (packed), z=3 -> wot
__global__ __launch_bounds__(256) void k_transpose_w(const float* __restrict__ Wq, const float* __restrict__ Wk,
                                                     const float* __restrict__ Wv, const float* __restrict__ Wo,
                                                     u16* __restrict__ wqkv, u16* __restrict__ wot) {
    __shared__ float tile[32][33];
    int z = blockIdx.z;
    const float* W = z == 0 ? Wq : z == 1 ? Wk : z == 2 ? Wv : Wo;
    u16* out = z < 3 ? (wqkv + (size_t)z * DIM * DIM) : wot;
    int tx = threadIdx.x, ty = threadIdx.y;        // (32, 8)
    int c0 = blockIdx.x * 32, r0 = blockIdx.y * 32;
#pragma unroll
    for (int i = 0; i < 4; i++)
        tile[ty + i * 8][tx] = W[(size_t)(r0 + ty + i * 8) * DIM + c0 + tx];
    __syncthreads();
#pragma unroll
    for (int i = 0; i < 4; i++)
        out[(size_t)(c0 + ty + i * 8) * DIM + r0 + tx] = f2bf(tile[tx][ty + i * 8]);
}

// ---------------- cos/sin table + packed qkv bias ----------------
__global__ __launch_bounds__(256) void k_prep(const float* __restrict__ fr, const float* __restrict__ bq,
                                              const float* __restrict__ bk, const float* __restrict__ bv,
                                              float2* __restrict__ cs, float* __restrict__ bqkv) {
    int gid = blockIdx.x * 256 + threadIdx.x;      // 262144 threads
    float f = fr[gid];
    cs[gid] = make_float2(cosf(f), sinf(f));
    if (gid < 3 * DIM)
        bqkv[gid] = gid < DIM ? bq[gid] : gid < 2 * DIM ? bk[gid - DIM] : bv[gid - 2 * DIM];
}

// ---------------- GEMM: C = A @ B^T + bias ----------------
// A [M x K] bf16 row-major, B [N x K] bf16 row-major (pre-transposed weight).
// mode 0: write bf16 head-major q/k/v (N=4608). mode 1: write fp32 [M][DIM].
__global__ __launch_bounds__(256) void k_gemm(const u16* __restrict__ A, const u16* __restrict__ B,
                                              const float* __restrict__ bias, int Kdim, int mode,
                                              u16* __restrict__ qo, u16* __restrict__ ko,
                                              u16* __restrict__ vo, float* __restrict__ outf) {
    __shared__ u16 As[128 * 32];
    __shared__ u16 Bs[128 * 32];
    const int tid = threadIdx.x;
    const int w = tid >> 6, l = tid & 63;
    const int wr = w >> 1, wc = w & 1;
    const int lr = l & 15, lg = l >> 4;
    const int m0 = blockIdx.y * 128, n0 = blockIdx.x * 128;
    f32x4 acc[4][4] = {};

    // staging: chunk c covers LDS rows c*16..c*16+15 (64B rows).
    // swizzle: phys_byte(row, cb) = row*64 + (cb ^ ((row&3)<<4))
    const int srow = l >> 2;                                       // row within chunk
    const int scol = (((l & 3) * 16) ^ (((l >> 2) & 3) << 4)) >> 1; // source k-elems (pre-swizzled)

    for (int kt = 0; kt < Kdim; kt += 32) {
        __syncthreads();
#pragma unroll
        for (int c2 = 0; c2 < 2; ++c2) {
            int c = w * 2 + c2;
            int row = c * 16 + srow;
            GLL(A + (size_t)(m0 + row) * Kdim + kt + scol, As + c * 512);
            GLL(B + (size_t)(n0 + row) * Kdim + kt + scol, Bs + c * 512);
        }
        __syncthreads();
        bf16x8 af[4], bg[4];
#pragma unroll
        for (int i = 0; i < 4; i++) {
            int co = (lg * 8) ^ ((lr & 3) << 3);                   // swizzled read (elems)
            af[i] = *(const bf16x8*)(As + (wr * 64 + i * 16 + lr) * 32 + co);
            bg[i] = *(const bf16x8*)(Bs + (wc * 64 + i * 16 + lr) * 32 + co);
        }
#pragma unroll
        for (int i = 0; i < 4; i++)
#pragma unroll
            for (int j = 0; j < 4; j++)
                acc[i][j] = __builtin_amdgcn_mfma_f32_16x16x32_bf16(af[i], bg[j], acc[i][j], 0, 0, 0);
    }

#pragma unroll
    for (int j = 0; j < 4; j++) {
        int gc = n0 + wc * 64 + j * 16 + lr;
        float bb = bias[gc];
#pragma unroll
        for (int i = 0; i < 4; i++) {
            int gr0 = m0 + wr * 64 + i * 16 + lg * 4;
            if (mode == 0) {
                int t = gc / DIM;
                int rr = gc % DIM;
                int hh = rr >> 7, hd = rr & 127;
                u16* dst = t == 0 ? qo : t == 1 ? ko : vo;
                size_t base = (size_t)hh * SEQ * HD + hd;
#pragma unroll
                for (int r = 0; r < 4; r++)
                    dst[base + (size_t)(gr0 + r) * HD] = f2bf(acc[i][j][r] + bb);
            } else {
#pragma unroll
                for (int r = 0; r < 4; r++)
                    outf[(size_t)(gr0 + r) * DIM + gc] = acc[i][j][r] + bb;
            }
        }
    }
}

// ---------------- RoPE on q,k (in place) ----------------
__global__ __launch_bounds__(256) void k_rope(u16* __restrict__ qb, u16* __restrict__ kb,
                                              const float2* __restrict__ cs) {
    int gid = blockIdx.x * 256 + threadIdx.x;      // 2 * 12*4096*64 threads
    const int T = NH * SEQ * 64;
    u16* buf = gid < T ? qb : kb;
    int r = gid < T ? gid : gid - T;
    int hh = r / (SEQ * 64);
    int rr = r % (SEQ * 64);
    int ll = rr >> 6, ii = rr & 63;
    size_t off = ((size_t)hh * SEQ + ll) * HD + 2 * ii;
    u32 pk = *(const u32*)(buf + off);
    float x0 = bf2f((u16)(pk & 0xFFFFu)), x1 = bf2f((u16)(pk >> 16));
    float2 c = cs[ll * 64 + ii];
    float r0 = x0 * c.x - x1 * c.y;
    float r1 = x0 * c.y + x1 * c.x;
    *(u32*)(buf + off) = pack2(r0, r1);
}

// ---------------- flash attention ----------------
// block: 256 thr (4 waves), 64 q-rows (16/wave), KTILE=32, online softmax.
__global__ __launch_bounds__(256) void k_attn(const u16* __restrict__ qb, const u16* __restrict__ kb,
                                              const u16* __restrict__ vb, u16* __restrict__ attnb) {
    __shared__ u16 Ks[32 * 128];    // swizzled: phys(row,cb) = row*256 + (cb ^ ((row&7)<<4))
    __shared__ u16 Vt[128 * 40];    // transposed V, padded stride 40
    __shared__ u16 Pl[4 * 16 * 40]; // per-wave P, padded stride 40
    const int tid = threadIdx.x;
    const int w = tid >> 6, l = tid & 63;
    const int lr = l & 15, lg = l >> 4;
    const int h = blockIdx.y;
    const int q0 = blockIdx.x * 64;
    const size_t hb = (size_t)h * SEQ * HD;
    constexpr float SCL2 = 0.08838834764831845f * 1.4426950408889634f; // 1/sqrt(128) * log2(e)

    bf16x8 qf[4];
    {
        int qrow = q0 + w * 16 + lr;
#pragma unroll
        for (int c = 0; c < 4; c++)
            qf[c] = *(const bf16x8*)(qb + hb + (size_t)qrow * HD + c * 32 + lg * 8);
    }
    f32x4 O[8] = {};
    float mrow[4] = {-1e30f, -1e30f, -1e30f, -1e30f};
    float lrow[4] = {0.f, 0.f, 0.f, 0.f};
    const int vkey = tid & 31;

    for (int kt = 0; kt < SEQ; kt += 32) {
        __syncthreads();
        // stage K via global_load_lds, source pre-swizzled
#pragma unroll
        for (int c = 0; c < 2; c++) {
            int cc = w * 2 + c;
            int key = cc * 4 + lg;
            int d0 = (((lr * 16) ^ ((key & 7) << 4)) >> 1);
            GLL(kb + hb + (size_t)(kt + key) * HD + d0, Ks + cc * 512);
        }
        // stage V transposed (reg-staged)
#pragma unroll
        for (int rr = 0; rr < 2; rr++) {
            int d0 = ((tid >> 5) + rr * 8) * 8;
            uint4 vv = *(const uint4*)(vb + hb + (size_t)(kt + vkey) * HD + d0);
            u32 w0 = vv.x, w1 = vv.y, w2 = vv.z, w3 = vv.w;
            Vt[(d0 + 0) * 40 + vkey] = (u16)(w0 & 0xFFFFu);
            Vt[(d0 + 1) * 40 + vkey] = (u16)(w0 >> 16);
            Vt[(d0 + 2) * 40 + vkey] = (u16)(w1 & 0xFFFFu);
            Vt[(d0 + 3) * 40 + vkey] = (u16)(w1 >> 16);
            Vt[(d0 + 4) * 40 + vkey] = (u16)(w2 & 0xFFFFu);
            Vt[(d0 + 5) * 40 + vkey] = (u16)(w2 >> 16);
            Vt[(d0 + 6) * 40 + vkey] = (u16)(w3 & 0xFFFFu);
            Vt[(d0 + 7) * 40 + vkey] = (u16)(w3 >> 16);
        }
        __syncthreads();

        // S = Q K^T  (C-layout: row=q=lg*4+r, col=key=lr)
        f32x4 S[2] = {};
#pragma unroll
        for (int j = 0; j < 2; j++) {
            int row = j * 16 + lr;
#pragma unroll
            for (int c = 0; c < 4; c++) {
                int cb = ((c * 64 + lg * 16) ^ ((row & 7) << 4)) >> 1;
                bf16x8 kf = *(const bf16x8*)(Ks + row * 128 + cb);
                S[j] = __builtin_amdgcn_mfma_f32_16x16x32_bf16(qf[c], kf, S[j], 0, 0, 0);
            }
        }
        // online softmax (log2 domain)
        float alpha[4];
#pragma unroll
        for (int r = 0; r < 4; r++) {
            float s0 = S[0][r] * SCL2;
            float s1 = S[1][r] * SCL2;
            float mx = fmaxf(s0, s1);
            mx = fmaxf(mx, __shfl_xor(mx, 1));
            mx = fmaxf(mx, __shfl_xor(mx, 2));
            mx = fmaxf(mx, __shfl_xor(mx, 4));
            mx = fmaxf(mx, __shfl_xor(mx, 8));
            float mn = fmaxf(mrow[r], mx);
            float al = exp2f(mrow[r] - mn);
            float p0 = exp2f(s0 - mn);
            float p1 = exp2f(s1 - mn);
            mrow[r] = mn;
            float rs = p0 + p1;
            rs += __shfl_xor(rs, 1);
            rs += __shfl_xor(rs, 2);
            rs += __shfl_xor(rs, 4);
            rs += __shfl_xor(rs, 8);
            lrow[r] = lrow[r] * al + rs;
            alpha[r] = al;
            S[0][r] = p0; S[1][r] = p1;
        }
#pragma unroll
        for (int f = 0; f < 8; f++)
#pragma unroll
            for (int r = 0; r < 4; r++)
                O[f][r] *= alpha[r];
        // P -> LDS (wave-private), then PV
#pragma unroll
        for (int j = 0; j < 2; j++)
#pragma unroll
            for (int r = 0; r < 4; r++)
                Pl[w * 640 + (lg * 4 + r) * 40 + j * 16 + lr] = f2bf(S[j][r]);
        bf16x8 pa = *(const bf16x8*)(Pl + w * 640 + lr * 40 + lg * 8);
#pragma unroll
        for (int f = 0; f < 8; f++) {
            bf16x8 vf = *(const bf16x8*)(Vt + (f * 16 + lr) * 40 + lg * 8);
            O[f] = __builtin_amdgcn_mfma_f32_16x16x32_bf16(pa, vf, O[f], 0, 0, 0);
        }
    }
    // epilogue: attn [SEQ][DIM] bf16
#pragma unroll
    for (int f = 0; f < 8; f++) {
        int col = h * HD + f * 16 + lr;
#pragma unroll
        for (int r = 0; r < 4; r++) {
            int row = q0 + w * 16 + lg * 4 + r;
            attnb[(size_t)row * DIM + col] = f2bf(O[f][r] / lrow[r]);
        }
    }
}

extern "C" void kernel_launch(void* const* d_in, const int* in_sizes, int n_in,
                              void* d_out, int out_size, void* d_ws, size_t ws_size,
                              hipStream_t stream) {
    (void)in_sizes; (void)n_in; (void)out_size; (void)ws_size;
    const float* x  = (const float*)d_in[0];
    const float* fr = (const float*)d_in[1];
    const float* Wq = (const float*)d_in[2];
    const float* bq = (const float*)d_in[3];
    const float* Wk = (const float*)d_in[4];
    const float* bk = (const float*)d_in[5];
    const float* Wv = (const float*)d_in[6];
    const float* bv = (const float*)d_in[7];
    const float* Wo = (const float*)d_in[8];
    const float* bo = (const float*)d_in[9];
    float* out = (float*)d_out;

    char* ws = (char*)d_ws;
    size_t off = 0;
    auto alloc = [&](size_t b) { char* p = ws + off; off = (off + b + 255) & ~(size_t)255; return p; };
    u16*   xb    = (u16*)alloc((size_t)SEQ * DIM * 2);
    u16*   wqkv  = (u16*)alloc((size_t)3 * DIM * DIM * 2);
    u16*   wot   = (u16*)alloc((size_t)DIM * DIM * 2);
    float* bqkv  = (float*)alloc((size_t)3 * DIM * 4);
    u16*   qb    = (u16*)alloc((size_t)SEQ * DIM * 2);
    u16*   kb    = (u16*)alloc((size_t)SEQ * DIM * 2);
    u16*   vb    = (u16*)alloc((size_t)SEQ * DIM * 2);
    u16*   attnb = (u16*)alloc((size_t)SEQ * DIM * 2);
    float2* cs   = (float2*)alloc((size_t)SEQ * 64 * 8);

    k_cvt_x<<<3072, 256, 0, stream>>>(x, xb);
    k_transpose_w<<<dim3(48, 48, 4), dim3(32, 8), 0, stream>>>(Wq, Wk, Wv, Wo, wqkv, wot);
    k_prep<<<1024, 256, 0, stream>>>(fr, bq, bk, bv, cs, bqkv);
    k_gemm<<<dim3(36, 32), 256, 0, stream>>>(xb, wqkv, bqkv, DIM, 0, qb, kb, vb, nullptr);
    k_rope<<<24576, 256, 0, stream>>>(qb, kb, cs);
    k_attn<<<dim3(64, 12), 256, 0, stream>>>(qb, kb, vb, attnb);
    k_gemm<<<dim3(12, 32), 256, 0, stream>>>(attnb, wot, bo, DIM, 1, nullptr, nullptr, nullptr, out);
}

// Round 2
// 317.638 us; speedup vs baseline: 1.6940x; 1.6940x over previous
//
#include <hip/hip_runtime.h>

#define DIM 1536
#define NH  12
#define HD  128
#define SEQ 4096

typedef unsigned short u16;
typedef unsigned int   u32;
typedef __attribute__((ext_vector_type(8))) short bf16x8;
typedef __attribute__((ext_vector_type(4))) float f32x4;

static __device__ __forceinline__ u16 f2bf(float f) {
    u32 u = __float_as_uint(f);
    u32 r = u + 0x7FFFu + ((u >> 16) & 1u);
    return (u16)(r >> 16);
}
static __device__ __forceinline__ float bf2f(u16 h) {
    return __uint_as_float(((u32)h) << 16);
}
static __device__ __forceinline__ u32 pack2(float a, float b) {
    return (u32)f2bf(a) | ((u32)f2bf(b) << 16);
}

#define GLL(g, s) __builtin_amdgcn_global_load_lds( \
    (const __attribute__((address_space(1))) void*)(g), \
    (__attribute__((address_space(3))) void*)(s), 16, 0, 0)

// ---------------- x -> bf16 (8 elems/thread) ----------------
__global__ __launch_bounds__(256) void k_cvt_x(const float* __restrict__ x, u16* __restrict__ xb) {
    int gid = blockIdx.x * 256 + threadIdx.x;      // 786432 threads
    const float4* p = (const float4*)x + (size_t)gid * 2;
    float4 a = p[0], b = p[1];
    uint4 o;
    o.x = pack2(a.x, a.y); o.y = pack2(a.z, a.w);
    o.z = pack2(b.x, b.y); o.w = pack2(b.z, b.w);
    *(uint4*)(xb + (size_t)gid * 8) = o;
}

// ---------------- weight transpose + bf16 ----------------
__global__ __launch_bounds__(256) void k_transpose_w(const float* __restrict__ Wq, const float* __restrict__ Wk,
                                                     const float* __restrict__ Wv, const float* __restrict__ Wo,
                                                     u16* __restrict__ wqkv, u16* __restrict__ wot) {
    __shared__ float tile[32][33];
    int z = blockIdx.z;
    const float* W = z == 0 ? Wq : z == 1 ? Wk : z == 2 ? Wv : Wo;
    u16* out = z < 3 ? (wqkv + (size_t)z * DIM * DIM) : wot;
    int tx = threadIdx.x, ty = threadIdx.y;        // (32, 8)
    int c0 = blockIdx.x * 32, r0 = blockIdx.y * 32;
#pragma unroll
    for (int i = 0; i < 4; i++)
        tile[ty + i * 8][tx] = W[(size_t)(r0 + ty + i * 8) * DIM + c0 + tx];
    __syncthreads();
#pragma unroll
    for (int i = 0; i < 4; i++)
        out[(size_t)(c0 + ty + i * 8) * DIM + r0 + tx] = f2bf(tile[tx][ty + i * 8]);
}

// ---------------- V transpose: vb [h][l][d] -> vt [h][d][l] ----------------
__global__ __launch_bounds__(256) void k_tr_v(const u16* __restrict__ vb, u16* __restrict__ vt) {
    __shared__ u16 tile[32][33];
    int h = blockIdx.z;
    int l0 = blockIdx.x * 32, d0 = blockIdx.y * 32;
    int tx = threadIdx.x, ty = threadIdx.y;        // (32, 8)
    const u16* src = vb + (size_t)h * SEQ * HD;
    u16* dst = vt + (size_t)h * HD * SEQ;
#pragma unroll
    for (int i = 0; i < 4; i++)
        tile[ty + i * 8][tx] = src[(size_t)(l0 + ty + i * 8) * HD + d0 + tx];
    __syncthreads();
#pragma unroll
    for (int i = 0; i < 4; i++)
        dst[(size_t)(d0 + ty + i * 8) * SEQ + l0 + tx] = tile[tx][ty + i * 8];
}

// ---------------- cos/sin table + packed qkv bias ----------------
__global__ __launch_bounds__(256) void k_prep(const float* __restrict__ fr, const float* __restrict__ bq,
                                              const float* __restrict__ bk, const float* __restrict__ bv,
                                              float2* __restrict__ cs, float* __restrict__ bqkv) {
    int gid = blockIdx.x * 256 + threadIdx.x;      // 262144 threads
    float f = fr[gid];
    cs[gid] = make_float2(cosf(f), sinf(f));
    if (gid < 3 * DIM)
        bqkv[gid] = gid < DIM ? bq[gid] : gid < 2 * DIM ? bk[gid - DIM] : bv[gid - 2 * DIM];
}

// ---------------- GEMM: C = A @ B^T + bias ----------------
__global__ __launch_bounds__(256) void k_gemm(const u16* __restrict__ A, const u16* __restrict__ B,
                                              const float* __restrict__ bias, int Kdim, int mode,
                                              u16* __restrict__ qo, u16* __restrict__ ko,
                                              u16* __restrict__ vo, float* __restrict__ outf) {
    __shared__ u16 As[128 * 32];
    __shared__ u16 Bs[128 * 32];
    const int tid = threadIdx.x;
    const int w = tid >> 6, l = tid & 63;
    const int wr = w >> 1, wc = w & 1;
    const int lr = l & 15, lg = l >> 4;
    const int m0 = blockIdx.y * 128, n0 = blockIdx.x * 128;
    f32x4 acc[4][4] = {};

    const int srow = l >> 2;
    const int scol = (((l & 3) * 16) ^ (((l >> 2) & 3) << 4)) >> 1;

    for (int kt = 0; kt < Kdim; kt += 32) {
        __syncthreads();
#pragma unroll
        for (int c2 = 0; c2 < 2; ++c2) {
            int c = w * 2 + c2;
            int row = c * 16 + srow;
            GLL(A + (size_t)(m0 + row) * Kdim + kt + scol, As + c * 512);
            GLL(B + (size_t)(n0 + row) * Kdim + kt + scol, Bs + c * 512);
        }
        __syncthreads();
        bf16x8 af[4], bg[4];
#pragma unroll
        for (int i = 0; i < 4; i++) {
            int co = (lg * 8) ^ ((lr & 3) << 3);
            af[i] = *(const bf16x8*)(As + (wr * 64 + i * 16 + lr) * 32 + co);
            bg[i] = *(const bf16x8*)(Bs + (wc * 64 + i * 16 + lr) * 32 + co);
        }
#pragma unroll
        for (int i = 0; i < 4; i++)
#pragma unroll
            for (int j = 0; j < 4; j++)
                acc[i][j] = __builtin_amdgcn_mfma_f32_16x16x32_bf16(af[i], bg[j], acc[i][j], 0, 0, 0);
    }

#pragma unroll
    for (int j = 0; j < 4; j++) {
        int gc = n0 + wc * 64 + j * 16 + lr;
        float bb = bias[gc];
#pragma unroll
        for (int i = 0; i < 4; i++) {
            int gr0 = m0 + wr * 64 + i * 16 + lg * 4;
            if (mode == 0) {
                int t = gc / DIM;
                int rr = gc % DIM;
                int hh = rr >> 7, hd = rr & 127;
                u16* dst = t == 0 ? qo : t == 1 ? ko : vo;
                size_t base = (size_t)hh * SEQ * HD + hd;
#pragma unroll
                for (int r = 0; r < 4; r++)
                    dst[base + (size_t)(gr0 + r) * HD] = f2bf(acc[i][j][r] + bb);
            } else {
#pragma unroll
                for (int r = 0; r < 4; r++)
                    outf[(size_t)(gr0 + r) * DIM + gc] = acc[i][j][r] + bb;
            }
        }
    }
}

// ---------------- RoPE on q,k (in place) ----------------
__global__ __launch_bounds__(256) void k_rope(u16* __restrict__ qb, u16* __restrict__ kb,
                                              const float2* __restrict__ cs) {
    int gid = blockIdx.x * 256 + threadIdx.x;
    const int T = NH * SEQ * 64;
    u16* buf = gid < T ? qb : kb;
    int r = gid < T ? gid : gid - T;
    int hh = r / (SEQ * 64);
    int rr = r % (SEQ * 64);
    int ll = rr >> 6, ii = rr & 63;
    size_t off = ((size_t)hh * SEQ + ll) * HD + 2 * ii;
    u32 pk = *(const u32*)(buf + off);
    float x0 = bf2f((u16)(pk & 0xFFFFu)), x1 = bf2f((u16)(pk >> 16));
    float2 c = cs[ll * 64 + ii];
    float r0 = x0 * c.x - x1 * c.y;
    float r1 = x0 * c.y + x1 * c.x;
    *(u32*)(buf + off) = pack2(r0, r1);
}

// ---------------- flash attention ----------------
// 4 waves x 16 q-rows, KTILE=64, swapped QK^T (S^T=K@Q^T) -> lane-local softmax,
// cvt_pk + u32 LDS redistribute for P, V pre-transposed + GLL-staged.
__global__ __launch_bounds__(256, 3) void k_attn(const u16* __restrict__ qb, const u16* __restrict__ kbuf,
                                                 const u16* __restrict__ vt, u16* __restrict__ attnb) {
    __shared__ u16 Ks[64 * 128];      // swizzled: phys(row,b) = row*256 + (b ^ ((row&7)<<4))
    __shared__ u16 Vs[128 * 64];      // V^T tile, swizzled: phys(row,b) = row*128 + (b ^ ((row&7)<<4))
    __shared__ u32 Pl[4 * 16 * 36];   // per-wave [16 q][32 key-pairs], pad 36 (16B-aligned rows)
    const int tid = threadIdx.x;
    const int w = tid >> 6, l = tid & 63;
    const int lr = l & 15, lg = l >> 4;
    // XCD swizzle: 768 blocks = 8 XCD x 96; consecutive-on-XCD = same head
    int bid = blockIdx.x;
    int gw = (bid & 7) * 96 + (bid >> 3);
    const int h = gw >> 6;
    const int q0 = (gw & 63) << 6;
    const size_t hb = (size_t)h * SEQ * HD;
    constexpr float SCL2 = 0.08838834764831845f * 1.4426950408889634f; // 1/sqrt(128)*log2(e)
    constexpr float THR = 5.0f;

    bf16x8 qf[4];
    {
        int qrow = q0 + w * 16 + lr;
#pragma unroll
        for (int c = 0; c < 4; c++)
            qf[c] = *(const bf16x8*)(qb + hb + (size_t)qrow * HD + c * 32 + lg * 8);
    }
    f32x4 O[8] = {};
    float m_run = -1e30f, lsum = 0.f;
    u32* Plw = Pl + w * 576 + lr * 36;

    for (int kt = 0; kt < SEQ; kt += 64) {
        __syncthreads();
#pragma unroll
        for (int c = 0; c < 4; c++) {
            int cc = w * 4 + c;
            int key = cc * 4 + lg;
            int d0 = ((lr * 16) ^ ((key & 7) << 4)) >> 1;
            GLL(kbuf + hb + (size_t)(kt + key) * HD + d0, Ks + cc * 512);
            int dd = cc * 8 + (l >> 3);
            int c0 = (((l & 7) * 16) ^ ((l >> 3) << 4)) >> 1;
            GLL(vt + hb + (size_t)dd * SEQ + kt + c0, Vs + cc * 512);
        }
        __syncthreads();

        // S^T = K @ Q^T : lane holds q=lr, keys jb*16 + lg*4 + r
        f32x4 ST[4];
#pragma unroll
        for (int jb = 0; jb < 4; jb++) {
            f32x4 st = {};
            int row = jb * 16 + lr;
            int rx = (row & 7) << 4;
#pragma unroll
            for (int c = 0; c < 4; c++) {
                int cb = ((c * 64 + lg * 16) ^ rx) >> 1;
                bf16x8 kf = *(const bf16x8*)(Ks + row * 128 + cb);
                st = __builtin_amdgcn_mfma_f32_16x16x32_bf16(kf, qf[c], st, 0, 0, 0);
            }
            ST[jb] = st;
        }

        // lane-local max over 16 + 2 shuffles across lg
        float mx = ST[0][0];
#pragma unroll
        for (int jb = 0; jb < 4; jb++)
#pragma unroll
            for (int r = 0; r < 4; r++)
                mx = fmaxf(mx, ST[jb][r]);
        mx = fmaxf(mx, __shfl_xor(mx, 16));
        mx = fmaxf(mx, __shfl_xor(mx, 32));
        float mt = mx * SCL2;
        bool grow = mt > m_run + THR;
        float m_new = grow ? mt : m_run;
        if (__any(grow)) {
            float alpha = grow ? __builtin_amdgcn_exp2f(m_run - m_new) : 1.0f;
            lsum *= alpha;
            m_run = m_new;
            float aO[4];
#pragma unroll
            for (int r = 0; r < 4; r++)
                aO[r] = __shfl(alpha, lg * 4 + r);
#pragma unroll
            for (int f = 0; f < 8; f++)
#pragma unroll
                for (int r = 0; r < 4; r++)
                    O[f][r] *= aO[r];
        }
        float ps = 0.f;
#pragma unroll
        for (int jb = 0; jb < 4; jb++)
#pragma unroll
            for (int r = 0; r < 4; r++) {
                float p = __builtin_amdgcn_exp2f(fmaf(ST[jb][r], SCL2, -m_new));
                ST[jb][r] = p;
                ps += p;
            }
        lsum += ps;

        // pack P -> bf16 pairs (consecutive keys), wave-private LDS redistribute
#pragma unroll
        for (int jb = 0; jb < 4; jb++) {
            u32 p0, p1;
            asm("v_cvt_pk_bf16_f32 %0, %1, %2" : "=v"(p0) : "v"(ST[jb][0]), "v"(ST[jb][1]));
            asm("v_cvt_pk_bf16_f32 %0, %1, %2" : "=v"(p1) : "v"(ST[jb][2]), "v"(ST[jb][3]));
            Plw[jb * 8 + lg * 2 + 0] = p0;
            Plw[jb * 8 + lg * 2 + 1] = p1;
        }
        bf16x8 pa0 = *(const bf16x8*)(Plw + lg * 4);
        bf16x8 pa1 = *(const bf16x8*)(Plw + 16 + lg * 4);

        // O += P @ V  (b-frag from transposed V tile)
#pragma unroll
        for (int f = 0; f < 8; f++) {
            int vrow = f * 16 + lr;
            int rx = (vrow & 7) << 4;
            bf16x8 v0 = *(const bf16x8*)(Vs + vrow * 64 + (((lg * 16) ^ rx) >> 1));
            O[f] = __builtin_amdgcn_mfma_f32_16x16x32_bf16(pa0, v0, O[f], 0, 0, 0);
            bf16x8 v1 = *(const bf16x8*)(Vs + vrow * 64 + (((64 + lg * 16) ^ rx) >> 1));
            O[f] = __builtin_amdgcn_mfma_f32_16x16x32_bf16(pa1, v1, O[f], 0, 0, 0);
        }
    }

    lsum += __shfl_xor(lsum, 16);
    lsum += __shfl_xor(lsum, 32);
    float li[4];
#pragma unroll
    for (int r = 0; r < 4; r++)
        li[r] = 1.0f / __shfl(lsum, lg * 4 + r);
#pragma unroll
    for (int f = 0; f < 8; f++) {
        int col = h * HD + f * 16 + lr;
#pragma unroll
        for (int r = 0; r < 4; r++) {
            int row = q0 + w * 16 + lg * 4 + r;
            attnb[(size_t)row * DIM + col] = f2bf(O[f][r] * li[r]);
        }
    }
}

extern "C" void kernel_launch(void* const* d_in, const int* in_sizes, int n_in,
                              void* d_out, int out_size, void* d_ws, size_t ws_size,
                              hipStream_t stream) {
    (void)in_sizes; (void)n_in; (void)out_size; (void)ws_size;
    const float* x  = (const float*)d_in[0];
    const float* fr = (const float*)d_in[1];
    const float* Wq = (const float*)d_in[2];
    const float* bq = (const float*)d_in[3];
    const float* Wk = (const float*)d_in[4];
    const float* bk = (const float*)d_in[5];
    const float* Wv = (const float*)d_in[6];
    const float* bv = (const float*)d_in[7];
    const float* Wo = (const float*)d_in[8];
    const float* bo = (const float*)d_in[9];
    float* out = (float*)d_out;

    char* ws = (char*)d_ws;
    size_t off = 0;
    auto alloc = [&](size_t b) { char* p = ws + off; off = (off + b + 255) & ~(size_t)255; return p; };
    u16*   xb    = (u16*)alloc((size_t)SEQ * DIM * 2);
    u16*   wqkv  = (u16*)alloc((size_t)3 * DIM * DIM * 2);
    u16*   wot   = (u16*)alloc((size_t)DIM * DIM * 2);
    float* bqkv  = (float*)alloc((size_t)3 * DIM * 4);
    u16*   qb    = (u16*)alloc((size_t)SEQ * DIM * 2);
    u16*   kb    = (u16*)alloc((size_t)SEQ * DIM * 2);
    u16*   vb    = (u16*)alloc((size_t)SEQ * DIM * 2);
    u16*   vtb   = (u16*)alloc((size_t)SEQ * DIM * 2);
    u16*   attnb = (u16*)alloc((size_t)SEQ * DIM * 2);
    float2* cs   = (float2*)alloc((size_t)SEQ * 64 * 8);

    k_cvt_x<<<3072, 256, 0, stream>>>(x, xb);
    k_transpose_w<<<dim3(48, 48, 4), dim3(32, 8), 0, stream>>>(Wq, Wk, Wv, Wo, wqkv, wot);
    k_prep<<<1024, 256, 0, stream>>>(fr, bq, bk, bv, cs, bqkv);
    k_gemm<<<dim3(36, 32), 256, 0, stream>>>(xb, wqkv, bqkv, DIM, 0, qb, kb, vb, nullptr);
    k_rope<<<24576, 256, 0, stream>>>(qb, kb, cs);
    k_tr_v<<<dim3(128, 4, 12), dim3(32, 8), 0, stream>>>(vb, vtb);
    k_attn<<<768, 256, 0, stream>>>(qb, kb, vtb, attnb);
    k_gemm<<<dim3(12, 32), 256, 0, stream>>>(attnb, wot, bo, DIM, 1, nullptr, nullptr, nullptr, out);
}